// Round 10
// baseline (130.755 us; speedup 1.0000x reference)
//
#include <hip/hip_runtime.h>
#include <stdint.h>

// Problem constants (fixed by reference)
#define N_IMG   16
#define C_IN    256
#define H_IN    32
#define W_IN    32
#define OH      30
#define OW      30
#define K_SEL   1152                   // C*KH*KW/2
#define OUTC    512
#define RY_TOT  (N_IMG * OH)           // 480 (n,y) rows
#define M_HAT   (RY_TOT * 32)          // 15360 = padded M (ow 30 -> 32)
#define X_ELEMS (N_IMG * C_IN * H_IN * W_IN)   // 4194304
#define OUT_SP  (OH * OW)              // 900
#define CHW     (C_IN * H_IN * W_IN)   // 262144

#define TO      256                    // o-tile
#define TM      64                     // m-tile = 2 ry rows x 32 xw
#define NMT     (M_HAT / TM)           // 240
#define NOT     (OUTC / TO)            // 2
#define BK      64                     // R10: k-step 32 -> 64 (halve step count)
#define BSTR    72                     // Bs row stride (shorts): 144B rows, 16B-aligned
#define KIT2    (K_SEL / BK)           // 18 k-steps

typedef float f32x4  __attribute__((ext_vector_type(4)));
typedef short bf16x8 __attribute__((ext_vector_type(8)));   // 8 bf16 = 4 VGPRs

__device__ __forceinline__ unsigned short f2bf(float f) {   // fp32 -> bf16 RNE
    unsigned int u = __float_as_uint(f);
    u += 0x7FFFu + ((u >> 16) & 1u);
    return (unsigned short)(u >> 16);
}

// async global->LDS, 16B/lane; LDS dst wave-uniform base, HW adds lane*16.
__device__ __forceinline__ void gl_lds16(const void* g, void* lds) {
    __builtin_amdgcn_global_load_lds(
        (const __attribute__((address_space(1))) unsigned int*)g,
        (__attribute__((address_space(3))) unsigned int*)lds,
        16, 0, 0);
}

// ---------------------------------------------------------------------------
// Prep: koff decode + coalesced LDS-tile transpose w(K_SEL x OUTC fp32) ->
// wT(OUTC x K_SEL bf16). Grid (36 s-tiles, 16 o-tiles) x 256 thr.
// ---------------------------------------------------------------------------
__global__ void prep_kernel(const int* __restrict__ idx, const float* __restrict__ w,
                            int* __restrict__ koff, unsigned short* __restrict__ wT) {
    __shared__ float tile[32][33];                 // +1 pad: phase1 conflict-free
    const int bx = blockIdx.x, by = blockIdx.y, t = threadIdx.x;

    if (by == 0) {                                 // fold koff decode into first row
        int k = bx * 256 + t;
        if (k < K_SEL) {
            int v = idx[k];
            int c = v / 9, rem = v - c * 9;
            int i = rem / 3, j = rem - i * 3;
            koff[k] = c * (H_IN * W_IN) + i * W_IN + j;
        }
    }
    const int s0 = bx * 32, o0 = by * 32;
    const int oc = t & 31, sg = t >> 5;
#pragma unroll
    for (int i = 0; i < 4; ++i) {                  // coalesced 128B reads along o
        int sl = sg * 4 + i;
        tile[sl][oc] = w[(s0 + sl) * OUTC + o0 + oc];
    }
    __syncthreads();
    const int ol = t >> 3, sq = t & 7;             // write along s: coalesced
    unsigned int u0 = (unsigned int)f2bf(tile[sq * 4 + 0][ol]) |
                      ((unsigned int)f2bf(tile[sq * 4 + 1][ol]) << 16);
    unsigned int u1 = (unsigned int)f2bf(tile[sq * 4 + 2][ol]) |
                      ((unsigned int)f2bf(tile[sq * 4 + 3][ol]) << 16);
    uint2 pk; pk.x = u0; pk.y = u1;
    *reinterpret_cast<uint2*>(&wT[(size_t)(o0 + ol) * K_SEL + s0 + sq * 4]) = pk;
}

// ---------------------------------------------------------------------------
// Fused GEMM: out[n,o,y,x] = sum_k wT[o][k] * x[n, koff[k] + y*32 + xw]
// Tile 256o x 64m, BK=64, 480 blocks.
// R10 theory: R9 measured 3230 cy/step vs ~600 cy of work -> a FIXED
// per-step cost (barrier + wait chain + issue serialization) dominates and
// absorbed R9's 2x work increase. Halve the step count: BK 32->64, 18
// steps. Per step 2x work (32 MFMA, 16 gathers, 8 gl_lds) but ONE barrier/
// vmcnt/koS-read. Skeleton = R9; As single-buffer WAVE-PRIVATE (R4-proven:
// frag reads -> lgkmcnt(0) -> sched_barrier -> gl_lds overwrite) to fit
// LDS 55KB (2 blocks/CU of 160KB).
// A-swizzle (row=128B): LDS (row r, 16B-chunk c) holds data chunk
// c^(r&7); gl_lds source pre-swizzled with cs=(lane&7)^(lane>>3); read
// chunk cd=kk*4+quad fetched at cs=cd^(lo&7) -> banks spread full 32,
// 2-way only (free, m136).
// Ledger: 24 VMEM/step issued as [8 gl_lds, 16 gathers].
//   top of kt: outstanding = gl(kt)[8] + ga(kt+1)[16] = 24.
//   vmcnt(16): drains gl(kt) -> As(kt) staged. frag reads (regs), lgkm 0,
//   sched_barrier, issue gl(kt+1)[8] + ga(kt+2)[16] -> 40.
//   vmcnt(24): drains ga(kt+1) -> pack source ready. pack -> Bs[q];
//   32 MFMA from regs; lgkmcnt(0); barrier. Prologue establishes 24.
// Bs 2-deep: pack(kt+1)->Bs[q]@kt, read@kt+1 after barrier; WAR read@kt-1
// -> write@kt separated by barrier@kt-1 (R3/R9-verified pattern).
// Tail: clamped dup loads keep counts uniform (R3-verified).
// ---------------------------------------------------------------------------
__global__ __launch_bounds__(256, 2)
void gemm_kernel(const unsigned short* __restrict__ wT, const float* __restrict__ x,
                 const int* __restrict__ koff, float* __restrict__ out) {
    __shared__ __align__(16) unsigned short As[TO * BK];       // 32KB, wave-private rows
    __shared__ __align__(16) unsigned short Bs[2][TM * BSTR];  // 2 x 9KB
    __shared__ int koS[K_SEL];                                 // 4.6KB

    const int t    = threadIdx.x;
    const int wave = t >> 6;
    const int lane = t & 63;
    const int quad = lane >> 4;
    const int lo   = lane & 15;

    const int bid = blockIdx.x;
    const int mt  = bid % NMT;                     // consecutive bids -> consecutive mt
    const int ot  = bid / NMT;                     // ot-siblings 240 apart -> same XCD
    const int oBase = ot * TO;
    const int mBase = mt * TM;

    for (int i = t; i < K_SEL; i += 256) koS[i] = koff[i];

    const int xw  = t & 31;                        // spatial lane within ry row
    const int xwc = min(xw, 29);                   // clamp: all gathers in-bounds (proven)
    int basex[2];
#pragma unroll
    for (int ry = 0; ry < 2; ++ry) {
        int ryg = mt * 2 + ry;
        int n = ryg / 30, y = ryg - n * 30;
        basex[ry] = n * CHW + y * W_IN + xwc;
    }

    const int kq = t >> 5;                         // 0..7 -> 8 k's each (BK=64)
    const int ks = kq * 8;

    // A staging: each wave owns 64 o-rows (= rows wave*64..+63), 8 gl_lds16
    // of 1KB per k-step. gl_lds i covers rows i*8..i*8+7; lane l -> row
    // (l>>3), chunk (l&7); source chunk pre-swizzled cs = (l&7)^(l>>3).
    const int arow = lane >> 3, csw = (lane & 7) ^ arow;
    const unsigned short* wrow[8];
#pragma unroll
    for (int i = 0; i < 8; ++i)
        wrow[i] = wT + (size_t)(oBase + wave * 64 + i * 8 + arow) * K_SEL + csw * 8;
    unsigned short* lA[8];
#pragma unroll
    for (int i = 0; i < 8; ++i)
        lA[i] = &As[(wave * 64 + i * 8) * BK];

    // A-frag read base: row wave*64 + ms*16 + lo, chunk (kk*4+quad)^(lo&7).
    const int ac0 = (quad ^ (lo & 7)) * 8;         // kk=0 chunk offset (shorts)
    const unsigned short* aBase = &As[(wave * 64 + lo) * BK];
    // B-frag read base: row ns*16+lo, shorts kk*32 + quad*8.
    const unsigned short* bB[2] = {
        &Bs[0][lo * BSTR + quad * 8],
        &Bs[1][lo * BSTR + quad * 8] };
    unsigned short* bW[2] = {
        &Bs[0][xw * BSTR + ks],
        &Bs[1][xw * BSTR + ks] };

    __syncthreads();                               // koS ready (one-time drain ok)

    f32x4 acc[4][4] = {};
    float v[2][2][8];                              // v[tile&1][ry][8 k's]

#define GATHER(KT, SLOT) do {                                                  \
    int4 k4a = *(const int4*)&koS[(KT) * BK + ks];                             \
    int4 k4b = *(const int4*)&koS[(KT) * BK + ks + 4];                         \
    _Pragma("unroll")                                                          \
    for (int ry = 0; ry < 2; ++ry)                                             \
        _Pragma("unroll")                                                      \
        for (int j = 0; j < 4; ++j) {                                          \
            v[SLOT][ry][j]     = x[basex[ry] + ((const int*)&k4a)[j]];         \
            v[SLOT][ry][4 + j] = x[basex[ry] + ((const int*)&k4b)[j]];         \
        }                                                                      \
} while (0)

#define PACK(SLOT, DST) do {                                                   \
    _Pragma("unroll")                                                          \
    for (int ry = 0; ry < 2; ++ry) {                                           \
        uint2 pk0, pk1;                                                        \
        pk0.x = (unsigned int)f2bf(v[SLOT][ry][0]) |                           \
                ((unsigned int)f2bf(v[SLOT][ry][1]) << 16);                    \
        pk0.y = (unsigned int)f2bf(v[SLOT][ry][2]) |                           \
                ((unsigned int)f2bf(v[SLOT][ry][3]) << 16);                    \
        pk1.x = (unsigned int)f2bf(v[SLOT][ry][4]) |                           \
                ((unsigned int)f2bf(v[SLOT][ry][5]) << 16);                    \
        pk1.y = (unsigned int)f2bf(v[SLOT][ry][6]) |                           \
                ((unsigned int)f2bf(v[SLOT][ry][7]) << 16);                    \
        *reinterpret_cast<uint2*>(bW[DST] + ry * 32 * BSTR)     = pk0;         \
        *reinterpret_cast<uint2*>(bW[DST] + ry * 32 * BSTR + 4) = pk1;         \
    }                                                                          \
} while (0)

    // ---- prologue: pack t0 -> Bs[0]; leave gl(t0)[8] + ga(t1)[16] = 24 ----
    GATHER(0, 0);
    asm volatile("s_waitcnt vmcnt(0)" ::: "memory");
    PACK(0, 0);
#pragma unroll
    for (int i = 0; i < 8; ++i) gl_lds16(wrow[i], lA[i]);      // gl(t0): 8
    GATHER(1, 1);                                              // ga(t1): 16
    asm volatile("s_waitcnt lgkmcnt(0)" ::: "memory");         // Bs[0] writes done
    __builtin_amdgcn_s_barrier();                              // Bs[0] visible

    // ---- main loop: 18 steps, 1 barrier each, 24 loads live across it ----
    for (int kt = 0; kt < KIT2; ++kt) {
        const int p = kt & 1, q = p ^ 1;

        // As(kt) staged: drain prev gl (keep prev 16 gathers).
        asm volatile("s_waitcnt vmcnt(16)" ::: "memory");
        // frag reads -> regs (a: 8 x b128 swizzled; b: 8 x b128 from Bs[p])
        bf16x8 a[4][2], b[4][2];
#pragma unroll
        for (int ms = 0; ms < 4; ++ms) {
            a[ms][0] = *(const bf16x8*)(aBase + ms * 16 * BK + ac0);
            a[ms][1] = *(const bf16x8*)(aBase + ms * 16 * BK + (ac0 ^ 32));
        }
#pragma unroll
        for (int ns = 0; ns < 4; ++ns) {
            b[ns][0] = *(const bf16x8*)(bB[p] + ns * 16 * BSTR);
            b[ns][1] = *(const bf16x8*)(bB[p] + ns * 16 * BSTR + 32);
        }
        asm volatile("s_waitcnt lgkmcnt(0)" ::: "memory");     // frags in regs
        __builtin_amdgcn_sched_barrier(0);                     // rule #18 fence

        // issue next-step VMEM: gl(kt+1) into As (rows consumed above), then
        // ga(kt+2) into v[p] (its old tile was packed last step).
        {
            const int k1 = (kt + 1 < KIT2 ? kt + 1 : KIT2 - 1) * BK;
#pragma unroll
            for (int i = 0; i < 8; ++i) gl_lds16(wrow[i] + k1, lA[i]);
        }
        GATHER((kt + 2 < KIT2 ? kt + 2 : KIT2 - 1), p);

        // pack source ready: drain prev gathers (keep this step's 24).
        asm volatile("s_waitcnt vmcnt(24)" ::: "memory");
        PACK(q, q);                                            // tile kt+1 -> Bs[q]

        // 32 MFMA, all operands in registers.
#pragma unroll
        for (int ms = 0; ms < 4; ++ms)
#pragma unroll
            for (int ns = 0; ns < 4; ++ns) {
                acc[ms][ns] = __builtin_amdgcn_mfma_f32_16x16x32_bf16(
                    a[ms][0], b[ns][0], acc[ms][ns], 0, 0, 0);
                acc[ms][ns] = __builtin_amdgcn_mfma_f32_16x16x32_bf16(
                    a[ms][1], b[ns][1], acc[ms][ns], 0, 0, 0);
            }

        asm volatile("s_waitcnt lgkmcnt(0)" ::: "memory");     // pack visible
        __builtin_amdgcn_s_barrier();
    }
#undef GATHER
#undef PACK

    // Epilogue: D row = o (quad*4+r), col = m (lane&15).
#pragma unroll
    for (int ns = 0; ns < 4; ++ns) {
        const int mh  = mBase + ns * 16 + lo;
        const int xwe = mh & 31;
        const int ryg = mh >> 5;
        const int n = ryg / 30, y = ryg - n * 30;
        if (xwe < OW) {
            const size_t ob = (size_t)n * (OUTC * OUT_SP) + (size_t)y * OW + xwe;
#pragma unroll
            for (int ms = 0; ms < 4; ++ms) {
                const int o0 = oBase + wave * 64 + ms * 16 + quad * 4;
#pragma unroll
                for (int r = 0; r < 4; ++r)
                    out[ob + (size_t)(o0 + r) * OUT_SP] = acc[ms][ns][r];
            }
        }
    }
}

// ---------------------------------------------------------------------------
extern "C" void kernel_launch(void* const* d_in, const int* in_sizes, int n_in,
                              void* d_out, int out_size, void* d_ws, size_t ws_size,
                              hipStream_t stream) {
    const float* x   = (const float*)d_in[0];
    const float* w   = (const float*)d_in[1];
    const int*   idx = (const int*)d_in[2];
    float*       out = (float*)d_out;

    // ws layout: koff 4608B | wT bf16 1179648B  (~1.2 MB total)
    char* ws = (char*)d_ws;
    int*            koff = (int*)ws;
    unsigned short* wT   = (unsigned short*)(ws + 4608);

    prep_kernel<<<dim3(K_SEL / 32, OUTC / 32), dim3(256), 0, stream>>>(idx, w, koff, wT);
    gemm_kernel<<<dim3(NMT * NOT), dim3(256), 0, stream>>>(wT, x, koff, out);
}

// Round 11
// 125.637 us; speedup vs baseline: 1.0407x; 1.0407x over previous
//
#include <hip/hip_runtime.h>
#include <stdint.h>

// Problem constants (fixed by reference)
#define N_IMG   16
#define C_IN    256
#define H_IN    32
#define W_IN    32
#define OH      30
#define OW      30
#define K_SEL   1152                   // C*KH*KW/2
#define OUTC    512
#define RY_TOT  (N_IMG * OH)           // 480 (n,y) rows
#define M_HAT   (RY_TOT * 32)          // 15360 = padded M (ow 30 -> 32)
#define X_ELEMS (N_IMG * C_IN * H_IN * W_IN)   // 4194304
#define OUT_SP  (OH * OW)              // 900
#define CHW     (C_IN * H_IN * W_IN)   // 262144

#define KITER   (K_SEL / 32)           // 36 k-steps of 32
#define NMT     240                    // m-tiles of 64 (2 ry x 32 xw)
#define NOW     8                      // o-wave tiles of 64

typedef float f32x4  __attribute__((ext_vector_type(4)));
typedef short bf16x8 __attribute__((ext_vector_type(8)));   // 8 bf16 = 4 VGPRs

__device__ __forceinline__ unsigned short f2bf(float f) {   // fp32 -> bf16 RNE
    unsigned int u = __float_as_uint(f);
    u += 0x7FFFu + ((u >> 16) & 1u);
    return (unsigned short)(u >> 16);
}

union Bpack { unsigned int w[4]; bf16x8 v; };

// ---------------------------------------------------------------------------
// Prep: koff decode + x->bf16 convert (xb) + w transpose into MFMA-FRAGMENT
// order wTf[ow][kt][ms][lane][8]: gemm A-loads become coalesced dwordx4.
// Grid (36 s-tiles, 16 o-tiles) x 256 thr (phase-2 tiling as before).
// ---------------------------------------------------------------------------
__global__ void prep_kernel(const int* __restrict__ idx, const float* __restrict__ w,
                            const float* __restrict__ x, int* __restrict__ koff,
                            unsigned short* __restrict__ xb,
                            unsigned short* __restrict__ wTf) {
    __shared__ float tile[32][33];                 // +1 pad: phase1 conflict-free
    const int bx = blockIdx.x, by = blockIdx.y, t = threadIdx.x;

    if (by == 0) {                                 // koff decode (1152 threads)
        int k = bx * 256 + t;
        if (k < K_SEL) {
            int v = idx[k];
            int c = v / 9, rem = v - c * 9;
            int i = rem / 3, j = rem - i * 3;
            koff[k] = c * (H_IN * W_IN) + i * W_IN + j;
        }
    }
    // x -> bf16 (grid-stride float4 over all 576 blocks)
    {
        const float4* x4 = (const float4*)x;
        ushort4* xb4 = (ushort4*)xb;
        const int gtid = (by * 36 + bx) * 256 + t;
        for (int i = gtid; i < X_ELEMS / 4; i += 36 * 16 * 256) {
            float4 f = x4[i];
            ushort4 u;
            u.x = f2bf(f.x); u.y = f2bf(f.y); u.z = f2bf(f.z); u.w = f2bf(f.w);
            xb4[i] = u;
        }
    }
    const int s0 = bx * 32, o0 = by * 32;
    const int oc = t & 31, sg = t >> 5;
#pragma unroll
    for (int i = 0; i < 4; ++i) {                  // coalesced 128B reads along o
        int sl = sg * 4 + i;
        tile[sl][oc] = w[(s0 + sl) * OUTC + o0 + oc];
    }
    __syncthreads();
    const int ol = t >> 3, sq = t & 7;             // read along s
    unsigned int u0 = (unsigned int)f2bf(tile[sq * 4 + 0][ol]) |
                      ((unsigned int)f2bf(tile[sq * 4 + 1][ol]) << 16);
    unsigned int u1 = (unsigned int)f2bf(tile[sq * 4 + 2][ol]) |
                      ((unsigned int)f2bf(tile[sq * 4 + 3][ol]) << 16);
    uint2 pk; pk.x = u0; pk.y = u1;
    // fragment-order index: o = by*32+ol -> ow=by>>1, ms=(by*2+(ol>>4))&3,
    // lo=ol&15; k = bx*32 + sq*4 + m -> kt=bx, quad=sq>>1, j0=(sq&1)*4.
    const size_t fi =
        (((((size_t)(by >> 1) * KITER + bx) * 4 + ((by * 2 + (ol >> 4)) & 3)) * 64
          + (sq >> 1) * 16 + (ol & 15)) * 8) + (sq & 1) * 4;
    *reinterpret_cast<uint2*>(&wTf[fi]) = pk;
}

// ---------------------------------------------------------------------------
// Fused GEMM, PURE-REGISTER dataflow (R11).
// Theory: R0-R10 fit wall = steps x step-latency with barrier-locked waves
// convoying through LDS/VALU staging phases (~3200cy/step vs ~500cy work).
// Fix: remove the machinery. No LDS tiles, no in-loop barriers.
//  * A: wTf is in fragment order -> 4 coalesced dwordx4 per step straight
//    into MFMA A-operand registers.
//  * B: per-lane ushort gathers from pre-converted xb (16-lane 32B
//    segments, L2-resident) + bit-pack -> B-frags. No cvt in loop.
//  * 1920 independent waves (240 mt x 8 ow, 64o x 64m each) ~= 2/SIMD,
//    whole grid co-resident; double-buffered register staging (named
//    buffers, literal indices only - rule #20) = 1-step prefetch.
// Per wave-step: 4 dwordx4 + 32 ushort + 2 koS reads + 16 pack VALU +
// 16 MFMA. MFMA floor 8.7us, L2 aggregate ~17us -> predict 15-25us.
// ---------------------------------------------------------------------------
__global__ __launch_bounds__(256, 2)
void gemm_kernel(const unsigned short* __restrict__ wTf,
                 const unsigned short* __restrict__ xb,
                 const int* __restrict__ koff, float* __restrict__ out) {
    __shared__ __align__(16) int koS[K_SEL];       // 4.6KB, read-only after init

    const int t    = threadIdx.x;
    const int wave = t >> 6;
    const int lane = t & 63;
    const int quad = lane >> 4;
    const int lo   = lane & 15;

    const int bid = blockIdx.x;
    const int mt  = bid % NMT;                     // consecutive bids -> consecutive mt
    const int og  = bid / NMT;                     // 0/1; 240 apart -> same XCD
    const int ow  = og * 4 + wave;                 // o-wave tile 0..7

    for (int i = t; i < K_SEL; i += 256) koS[i] = koff[i];
    __syncthreads();                               // only barrier in the kernel

    // B gather bases per ns: m = ns*16+lo -> ry=(ns>>1), xw=(ns&1)*16+lo
    int bns[4];
#pragma unroll
    for (int ns = 0; ns < 4; ++ns) {
        int ryg = mt * 2 + (ns >> 1);
        int n = ryg / 30, y = ryg - n * 30;
        int xw = (ns & 1) * 16 + lo;
        bns[ns] = n * CHW + y * W_IN + min(xw, 29);    // clamp: in-bounds (proven)
    }
    // A fragment pointer for this wave
    const unsigned short* aP = wTf + (size_t)ow * KITER * 4 * 64 * 8;

    f32x4 acc[4][4] = {};
    bf16x8 aR0[4], aR1[4];
    unsigned int u0[32], u1[32];                   // literal-indexed only
    int4 kof0a, kof0b, kof1a, kof1b;

    // ---- prologue: kof(0); issue tile 0 into buffers 0; kof(1) ----
    kof0a = *(const int4*)&koS[quad * 8];
    kof0b = *(const int4*)&koS[quad * 8 + 4];
#pragma unroll
    for (int ms = 0; ms < 4; ++ms)
        aR0[ms] = *(const bf16x8*)(aP + ((size_t)(0 * 4 + ms) * 64 + lane) * 8);
#pragma unroll
    for (int j = 0; j < 4; ++j) {
        const int ka = ((const int*)&kof0a)[j], kb = ((const int*)&kof0b)[j];
#pragma unroll
        for (int ns = 0; ns < 4; ++ns) {
            u0[ns * 8 + j]     = xb[bns[ns] + ka];
            u0[ns * 8 + 4 + j] = xb[bns[ns] + kb];
        }
    }
    kof1a = *(const int4*)&koS[32 + quad * 8];
    kof1b = *(const int4*)&koS[32 + quad * 8 + 4];

    // ---- main loop: 18 iterations x 2 substeps; no barriers ----
    for (int kt = 0; kt < KITER; kt += 2) {
        // even substep: prefetch kt+1 (buffers 1, kof1); compute kt (buffers 0)
        {
            const int kt1 = kt + 1;
#pragma unroll
            for (int ms = 0; ms < 4; ++ms)
                aR1[ms] = *(const bf16x8*)(aP + ((size_t)(kt1 * 4 + ms) * 64 + lane) * 8);
#pragma unroll
            for (int j = 0; j < 4; ++j) {
                const int ka = ((const int*)&kof1a)[j], kb = ((const int*)&kof1b)[j];
#pragma unroll
                for (int ns = 0; ns < 4; ++ns) {
                    u1[ns * 8 + j]     = xb[bns[ns] + ka];
                    u1[ns * 8 + 4 + j] = xb[bns[ns] + kb];
                }
            }
            const int kt2 = (kt + 2 < KITER) ? kt + 2 : KITER - 1;
            kof0a = *(const int4*)&koS[kt2 * 32 + quad * 8];
            kof0b = *(const int4*)&koS[kt2 * 32 + quad * 8 + 4];
            bf16x8 b[4];
#pragma unroll
            for (int ns = 0; ns < 4; ++ns) {
                Bpack bp;
                bp.w[0] = u0[ns * 8 + 0] | (u0[ns * 8 + 1] << 16);
                bp.w[1] = u0[ns * 8 + 2] | (u0[ns * 8 + 3] << 16);
                bp.w[2] = u0[ns * 8 + 4] | (u0[ns * 8 + 5] << 16);
                bp.w[3] = u0[ns * 8 + 6] | (u0[ns * 8 + 7] << 16);
                b[ns] = bp.v;
            }
#pragma unroll
            for (int ms = 0; ms < 4; ++ms)
#pragma unroll
                for (int ns = 0; ns < 4; ++ns)
                    acc[ms][ns] = __builtin_amdgcn_mfma_f32_16x16x32_bf16(
                        aR0[ms], b[ns], acc[ms][ns], 0, 0, 0);
        }
        // odd substep: prefetch kt+2 (buffers 0, kof0); compute kt+1 (buffers 1)
        {
            const int kt2 = (kt + 2 < KITER) ? kt + 2 : KITER - 1;
#pragma unroll
            for (int ms = 0; ms < 4; ++ms)
                aR0[ms] = *(const bf16x8*)(aP + ((size_t)(kt2 * 4 + ms) * 64 + lane) * 8);
#pragma unroll
            for (int j = 0; j < 4; ++j) {
                const int ka = ((const int*)&kof0a)[j], kb = ((const int*)&kof0b)[j];
#pragma unroll
                for (int ns = 0; ns < 4; ++ns) {
                    u0[ns * 8 + j]     = xb[bns[ns] + ka];
                    u0[ns * 8 + 4 + j] = xb[bns[ns] + kb];
                }
            }
            const int kt3 = (kt + 3 < KITER) ? kt + 3 : KITER - 1;
            kof1a = *(const int4*)&koS[kt3 * 32 + quad * 8];
            kof1b = *(const int4*)&koS[kt3 * 32 + quad * 8 + 4];
            bf16x8 b[4];
#pragma unroll
            for (int ns = 0; ns < 4; ++ns) {
                Bpack bp;
                bp.w[0] = u1[ns * 8 + 0] | (u1[ns * 8 + 1] << 16);
                bp.w[1] = u1[ns * 8 + 2] | (u1[ns * 8 + 3] << 16);
                bp.w[2] = u1[ns * 8 + 4] | (u1[ns * 8 + 5] << 16);
                bp.w[3] = u1[ns * 8 + 6] | (u1[ns * 8 + 7] << 16);
                b[ns] = bp.v;
            }
#pragma unroll
            for (int ms = 0; ms < 4; ++ms)
#pragma unroll
                for (int ns = 0; ns < 4; ++ns)
                    acc[ms][ns] = __builtin_amdgcn_mfma_f32_16x16x32_bf16(
                        aR1[ms], b[ns], acc[ms][ns], 0, 0, 0);
        }
    }

    // Epilogue (verified mapping): D row = o (quad*4+r), col = m (lane&15).
#pragma unroll
    for (int ns = 0; ns < 4; ++ns) {
        const int mh  = mt * 64 + ns * 16 + lo;
        const int xwe = mh & 31;
        const int ryg = mh >> 5;
        const int n = ryg / 30, y = ryg - n * 30;
        if (xwe < OW) {
            const size_t ob = (size_t)n * (OUTC * OUT_SP) + (size_t)y * OW + xwe;
#pragma unroll
            for (int ms = 0; ms < 4; ++ms) {
                const int o0 = ow * 64 + ms * 16 + quad * 4;
#pragma unroll
                for (int r = 0; r < 4; ++r)
                    out[ob + (size_t)(o0 + r) * OUT_SP] = acc[ms][ns][r];
            }
        }
    }
}

// ---------------------------------------------------------------------------
extern "C" void kernel_launch(void* const* d_in, const int* in_sizes, int n_in,
                              void* d_out, int out_size, void* d_ws, size_t ws_size,
                              hipStream_t stream) {
    const float* x   = (const float*)d_in[0];
    const float* w   = (const float*)d_in[1];
    const int*   idx = (const int*)d_in[2];
    float*       out = (float*)d_out;

    // ws layout: koff 4608B | wTf bf16 1179648B | xb bf16 8388608B (~9.6MB)
    char* ws = (char*)d_ws;
    int*            koff = (int*)ws;
    unsigned short* wTf  = (unsigned short*)(ws + 4608);
    unsigned short* xb   = (unsigned short*)(ws + 4608 + 1179648);

    prep_kernel<<<dim3(K_SEL / 32, OUTC / 32), dim3(256), 0, stream>>>(
        idx, w, x, koff, xb, wTf);
    gemm_kernel<<<dim3(NMT * 2), dim3(256), 0, stream>>>(wTf, xb, koff, out);
}

// Round 12
// 104.125 us; speedup vs baseline: 1.2558x; 1.2066x over previous
//
#include <hip/hip_runtime.h>
#include <stdint.h>

// Problem constants (fixed by reference)
#define N_IMG   16
#define C_IN    256
#define H_IN    32
#define W_IN    32
#define OH      30
#define OW      30
#define K_SEL   1152                   // C*KH*KW/2
#define OUTC    512
#define RY_TOT  (N_IMG * OH)           // 480 (n,y) rows
#define M_HAT   (RY_TOT * 32)          // 15360 = padded M (ow 30 -> 32)
#define X_ELEMS (N_IMG * C_IN * H_IN * W_IN)   // 4194304
#define OUT_SP  (OH * OW)              // 900
#define CHW     (C_IN * H_IN * W_IN)   // 262144

#define TO      128                    // o-tile (R3 geometry)
#define TM      64                     // m-tile = 2 ry rows x 32 xw
#define NMT     (M_HAT / TM)           // 240
#define NOT     (OUTC / TO)            // 4
#define BSTR    40                     // Bs row stride (shorts)
#define KITER   (K_SEL / 32)           // 36

typedef float f32x4  __attribute__((ext_vector_type(4)));
typedef short bf16x8 __attribute__((ext_vector_type(8)));   // 8 bf16 = 4 VGPRs

__device__ __forceinline__ unsigned short f2bf(float f) {   // fp32 -> bf16 RNE
    unsigned int u = __float_as_uint(f);
    u += 0x7FFFu + ((u >> 16) & 1u);
    return (unsigned short)(u >> 16);
}

// ---------------------------------------------------------------------------
// Prep (R11-verified): koff decode + w transpose into MFMA-FRAGMENT order
// wTf[ow64][kt][msIdx][lane][8] (o = ow64*64 + msIdx*16 + lo; k = kt*32 +
// quad*8 + j; lane = quad*16+lo). Gemm A-loads become coalesced dwordx4.
// ---------------------------------------------------------------------------
__global__ void prep_kernel(const int* __restrict__ idx, const float* __restrict__ w,
                            int* __restrict__ koff, unsigned short* __restrict__ wTf) {
    __shared__ float tile[32][33];                 // +1 pad: phase1 conflict-free
    const int bx = blockIdx.x, by = blockIdx.y, t = threadIdx.x;

    if (by == 0) {                                 // koff decode
        int k = bx * 256 + t;
        if (k < K_SEL) {
            int v = idx[k];
            int c = v / 9, rem = v - c * 9;
            int i = rem / 3, j = rem - i * 3;
            koff[k] = c * (H_IN * W_IN) + i * W_IN + j;
        }
    }
    const int s0 = bx * 32, o0 = by * 32;
    const int oc = t & 31, sg = t >> 5;
#pragma unroll
    for (int i = 0; i < 4; ++i) {                  // coalesced 128B reads along o
        int sl = sg * 4 + i;
        tile[sl][oc] = w[(s0 + sl) * OUTC + o0 + oc];
    }
    __syncthreads();
    const int ol = t >> 3, sq = t & 7;             // read along s
    unsigned int u0 = (unsigned int)f2bf(tile[sq * 4 + 0][ol]) |
                      ((unsigned int)f2bf(tile[sq * 4 + 1][ol]) << 16);
    unsigned int u1 = (unsigned int)f2bf(tile[sq * 4 + 2][ol]) |
                      ((unsigned int)f2bf(tile[sq * 4 + 3][ol]) << 16);
    uint2 pk; pk.x = u0; pk.y = u1;
    // fragment-order index (R11, end-to-end verified):
    const size_t fi =
        (((((size_t)(by >> 1) * KITER + bx) * 4 + ((by * 2 + (ol >> 4)) & 3)) * 64
          + (sq >> 1) * 16 + (ol & 15)) * 8) + (sq & 1) * 4;
    *reinterpret_cast<uint2*>(&wTf[fi]) = pk;
}

// ---------------------------------------------------------------------------
// Fused GEMM (R12): R3 skeleton (TO=128, 960 blocks, counted vmcnt, one
// barrier/step) with the ENTIRE A-path replaced by direct fragment loads
// from wTf (R11-verified layout): 2 coalesced dwordx4 per wave-step from L2
// straight into MFMA A-registers. No As tile, no gl_lds, no A ds_reads.
// Theory: R9's step cost center was the A-side LDS convoy (~1000cy/CU-step,
// barrier-locked) + <2 blocks/CU residency. This cuts LDS traffic ~4x and
// (LDS 15KB, VGPR~110, launch_bounds(256,4)) lets ~4 blocks/CU co-reside,
// overlapping the remaining phases across blocks.
// Ledger: 10 VMEM/step issued as [2 A-loads(kt+1), 8 gathers(kt+2)].
//   top of kt: outstanding = A(kt)[2] + ga(kt+1)[8] = 10.
//   after issuing this step's 10 -> 20; vmcnt(10) drains A(kt) (MFMA
//   operands) + ga(kt+1) (pack source). Compiler additionally auto-waits
//   on the register deps (plain C loads), so ordering is belt+suspenders.
// Bs 2-deep as R3: pack(kt+1)->Bs[q]@kt, read@kt+1; barrier separates all
// pack->read / read->repack pairs. Tail: clamped dup loads (R3-proven).
// ---------------------------------------------------------------------------
__global__ __launch_bounds__(256, 4)
void gemm_kernel(const unsigned short* __restrict__ wTf, const float* __restrict__ x,
                 const int* __restrict__ koff, float* __restrict__ out) {
    __shared__ __align__(16) unsigned short Bs[2][TM * BSTR];  // 2 x 5KB
    __shared__ int koS[K_SEL];                                 // 4.6KB

    const int t    = threadIdx.x;
    const int wave = t >> 6;
    const int lane = t & 63;
    const int quad = lane >> 4;
    const int lo   = lane & 15;

    const int bid = blockIdx.x;
    const int mt  = bid % NMT;                     // consecutive bids -> consecutive mt
    const int ot  = bid / NMT;                     // ot-siblings 240 apart -> same XCD
    const int oBase = ot * TO;
    const int mBase = mt * TM;

    for (int i = t; i < K_SEL; i += 256) koS[i] = koff[i];

    const int xw  = t & 31;                        // spatial lane within ry row
    const int xwc = min(xw, 29);                   // clamp: in-bounds (R4-verified)
    int basex[2];
#pragma unroll
    for (int ry = 0; ry < 2; ++ry) {
        int ryg = mt * 2 + ry;
        int n = ryg / 30, y = ryg - n * 30;
        basex[ry] = n * CHW + y * W_IN + xwc;
    }

    const int kq4 = t >> 5;                        // 0..7 -> 4 k's each
    const int ks  = kq4 * 4;

    // A fragment pointers: wave covers o rows oBase+wave*32 .. +63? No:
    // wave tile = 32 o rows (ms 0..1). ow64 = (oBase+wave*32)>>6 =
    // ot*2 + (wave>>1); msIdx(ms) = ((oBase+wave*32)>>4 + ms)&3 =
    // (wave*2+ms)&3 = idx0+ms with idx0=(wave*2)&3.
    const int ow64 = ot * 2 + (wave >> 1);
    const int idx0 = (wave * 2) & 3;
    const unsigned short* aP =
        wTf + ((size_t)ow64 * KITER * 4 + idx0) * 64 * 8 + (size_t)lane * 8;
    // aFrag(kt, ms): aP + (kt*4 + ms)*64*8

    const unsigned short* bB[2] = {
        &Bs[0][lo * BSTR + quad * 8],
        &Bs[1][lo * BSTR + quad * 8] };
    unsigned short* bW[2] = {
        &Bs[0][xw * BSTR + ks],
        &Bs[1][xw * BSTR + ks] };

    __syncthreads();                               // koS ready (one-time drain ok)

    f32x4 acc[2][4] = {};
    bf16x8 aR[2][2];                               // [buf][ms]
    float v[2][2][4];                              // v[tile&1][ry][j]

    // ---- prologue ----
    {
        int4 k4 = *(const int4*)&koS[ks];          // ga(t0): 8
#pragma unroll
        for (int ry = 0; ry < 2; ++ry)
#pragma unroll
            for (int j = 0; j < 4; ++j)
                v[0][ry][j] = x[basex[ry] + ((const int*)&k4)[j]];
    }
    asm volatile("s_waitcnt vmcnt(0)" ::: "memory");
#pragma unroll
    for (int ry = 0; ry < 2; ++ry) {               // pack t0 -> Bs[0]
        unsigned int u0 = (unsigned int)f2bf(v[0][ry][0]) |
                          ((unsigned int)f2bf(v[0][ry][1]) << 16);
        unsigned int u1 = (unsigned int)f2bf(v[0][ry][2]) |
                          ((unsigned int)f2bf(v[0][ry][3]) << 16);
        uint2 pk; pk.x = u0; pk.y = u1;
        *reinterpret_cast<uint2*>(bW[0] + ry * 32 * BSTR) = pk;
    }
#pragma unroll
    for (int ms = 0; ms < 2; ++ms)                 // A(t0): 2 -> aR[0]
        aR[0][ms] = *(const bf16x8*)(aP + (size_t)(0 * 4 + ms) * 64 * 8);
    {
        int4 k4 = *(const int4*)&koS[32 + ks];     // ga(t1): 8 -> 10 outstanding
#pragma unroll
        for (int ry = 0; ry < 2; ++ry)
#pragma unroll
            for (int j = 0; j < 4; ++j)
                v[1][ry][j] = x[basex[ry] + ((const int*)&k4)[j]];
    }
    asm volatile("s_waitcnt lgkmcnt(0)" ::: "memory");  // Bs[0] writes done
    __builtin_amdgcn_s_barrier();                       // Bs[0] visible

    // ---- main loop: 1 barrier per k-step, 10 loads live across it ----
#pragma unroll 2
    for (int kt = 0; kt < KITER; ++kt) {
        const int p = kt & 1, q = p ^ 1;

        // B-frags for this step (LDS)
        bf16x8 b[4];
#pragma unroll
        for (int ns = 0; ns < 4; ++ns)
            b[ns] = *(const bf16x8*)(bB[p] + ns * 16 * BSTR);

        // issue next A-frags and next-next gathers
        {
            const int k1 = (kt + 1 < KITER ? kt + 1 : KITER - 1);
#pragma unroll
            for (int ms = 0; ms < 2; ++ms)
                aR[q][ms] = *(const bf16x8*)(aP + (size_t)(k1 * 4 + ms) * 64 * 8);
        }
        {
            const int k2 = (kt + 2 < KITER ? kt + 2 : KITER - 1) * 32;
            int4 k4 = *(const int4*)&koS[k2 + ks];
#pragma unroll
            for (int ry = 0; ry < 2; ++ry)
#pragma unroll
                for (int j = 0; j < 4; ++j)
                    v[p][ry][j] = x[basex[ry] + ((const int*)&k4)[j]];
        }
        // counted drain: completes A(kt) (MFMA ops) + ga(kt+1) (pack source)
        asm volatile("s_waitcnt vmcnt(10)" ::: "memory");
        asm volatile("s_waitcnt lgkmcnt(0)" ::: "memory");  // b frags in regs
        __builtin_amdgcn_sched_barrier(0);
        // pack tile kt+1 -> Bs[q]
#pragma unroll
        for (int ry = 0; ry < 2; ++ry) {
            unsigned int u0 = (unsigned int)f2bf(v[q][ry][0]) |
                              ((unsigned int)f2bf(v[q][ry][1]) << 16);
            unsigned int u1 = (unsigned int)f2bf(v[q][ry][2]) |
                              ((unsigned int)f2bf(v[q][ry][3]) << 16);
            uint2 pk; pk.x = u0; pk.y = u1;
            *reinterpret_cast<uint2*>(bW[q] + ry * 32 * BSTR) = pk;
        }
        // compute tile kt: aR[p] x b -> 8 MFMA
#pragma unroll
        for (int ms = 0; ms < 2; ++ms)
#pragma unroll
            for (int ns = 0; ns < 4; ++ns)
                acc[ms][ns] = __builtin_amdgcn_mfma_f32_16x16x32_bf16(
                    aR[p][ms], b[ns], acc[ms][ns], 0, 0, 0);
        asm volatile("s_waitcnt lgkmcnt(0)" ::: "memory");  // pack visible
        __builtin_amdgcn_s_barrier();
    }

    // Epilogue (R3-verified): D row = o (quad*4+r), col = m (lane&15).
#pragma unroll
    for (int ns = 0; ns < 4; ++ns) {
        const int mh  = mBase + ns * 16 + lo;
        const int xwe = mh & 31;
        const int ryg = mh >> 5;
        const int n = ryg / 30, y = ryg - n * 30;
        if (xwe < OW) {
            const size_t ob = (size_t)n * (OUTC * OUT_SP) + (size_t)y * OW + xwe;
#pragma unroll
            for (int ms = 0; ms < 2; ++ms) {
                const int o0 = oBase + wave * 32 + ms * 16 + quad * 4;
#pragma unroll
                for (int r = 0; r < 4; ++r)
                    out[ob + (size_t)(o0 + r) * OUT_SP] = acc[ms][ns][r];
            }
        }
    }
}

// ---------------------------------------------------------------------------
extern "C" void kernel_launch(void* const* d_in, const int* in_sizes, int n_in,
                              void* d_out, int out_size, void* d_ws, size_t ws_size,
                              hipStream_t stream) {
    const float* x   = (const float*)d_in[0];
    const float* w   = (const float*)d_in[1];
    const int*   idx = (const int*)d_in[2];
    float*       out = (float*)d_out;

    // ws layout: koff 4608B | wTf bf16 1179648B (~1.2MB)
    char* ws = (char*)d_ws;
    int*            koff = (int*)ws;
    unsigned short* wTf  = (unsigned short*)(ws + 4608);

    prep_kernel<<<dim3(K_SEL / 32, OUTC / 32), dim3(256), 0, stream>>>(idx, w, koff, wTf);
    gemm_kernel<<<dim3(NMT * NOT), dim3(256), 0, stream>>>(wTf, x, koff, out);
}

// Round 14
// 103.698 us; speedup vs baseline: 1.2609x; 1.0041x over previous
//
#include <hip/hip_runtime.h>
#include <stdint.h>

// Problem constants (fixed by reference)
#define N_IMG   16
#define C_IN    256
#define H_IN    32
#define W_IN    32
#define OH      30
#define OW      30
#define K_SEL   1152                   // C*KH*KW/2
#define OUTC    512
#define RY_TOT  (N_IMG * OH)           // 480 (n,y) rows
#define M_HAT   (RY_TOT * 32)          // 15360 = padded M (ow 30 -> 32)
#define X_ELEMS (N_IMG * C_IN * H_IN * W_IN)   // 4194304
#define OUT_SP  (OH * OW)              // 900
#define CHW     (C_IN * H_IN * W_IN)   // 262144

#define TO      128                    // o-tile
#define TM      64                     // m-tile = 2 ry rows x 32 xw
#define NMT     (M_HAT / TM)           // 240
#define NOT     (OUTC / TO)            // 4
#define BSTR    40                     // (fallback) Bs row stride
#define KITER   (K_SEL / 32)           // 36

#define NPACK   (NMT * KITER)          // 8640 B-pack blocks
#define NPREPW  (36 * 16)              // 576 w-transpose blocks
#define WTF_BYTES 1179648u
#define BF_BYTES  35389440u            // 15360*1152*2

typedef float f32x4  __attribute__((ext_vector_type(4)));
typedef short bf16x8 __attribute__((ext_vector_type(8)));   // 8 bf16 = 4 VGPRs

__device__ __forceinline__ unsigned short f2bf(float f) {   // fp32 -> bf16 RNE
    unsigned int u = __float_as_uint(f);
    u += 0x7FFFu + ((u >> 16) & 1u);
    return (unsigned short)(u >> 16);
}

// async global->LDS, 16B/lane; LDS dst wave-uniform base, HW adds lane*16.
__device__ __forceinline__ void gl_lds16(const void* g, void* lds) {
    __builtin_amdgcn_global_load_lds(
        (const __attribute__((address_space(1))) unsigned int*)g,
        (__attribute__((address_space(3))) unsigned int*)lds,
        16, 0, 0);
}

// ===========================================================================
// R14 = R13 resubmission. R13 died at container level (no counters); audit
// found no defect (waitcnt ledger closed + compiler auto-waits make deadlock
// impossible; barriers uniform; all indices bounds-checked). Precedent: R2's
// identical container failure passed on byte-identical resubmit (R3).
// PATH A (big workspace): prep packs BOTH operands into MFMA-fragment order;
// gemm is a lean staged loop with zero gathers / pack VALU / koS.
// ===========================================================================

// ---------------------------------------------------------------------------
// prepA: blocks [0,8640) pack B: tile (mt,kt) -> Bf[(mt*36+kt)*2048 + t*8],
// thread t = ns*64+lane owns m=ns*16+(lane&15), k=kt*32+(lane>>4)*8+j
// (the R11/R12-verified fragment convention, shared with wTf).
// Blocks [8640,9216) transpose w into wTf (R12-verified body, koff-free).
// Gathers happen ONCE per mt (vs once per ot-sibling x4 in R12's gemm).
// ---------------------------------------------------------------------------
__global__ void prepA_kernel(const int* __restrict__ idx, const float* __restrict__ w,
                             const float* __restrict__ x,
                             unsigned short* __restrict__ wTf,
                             unsigned short* __restrict__ Bf) {
    __shared__ float tile[32][33];
    const int bid = blockIdx.x, t = threadIdx.x;

    if (bid < NPACK) {
        const int mt = bid / KITER, kt = bid - mt * KITER;
        const int lane = t & 63, ns = t >> 6;
        const int quad = lane >> 4, lo = lane & 15;
        const int m  = ns * 16 + lo;
        const int ry = m >> 5, xw = m & 31;
        const int ryg = mt * 2 + ry;
        const int n = ryg / 30, y = ryg - n * 30;
        const int base = n * CHW + y * W_IN + min(xw, 29);   // clamp: in-bounds
        unsigned int uu[4];
#pragma unroll
        for (int jp = 0; jp < 4; ++jp) {
            unsigned short ua, ub;
            {
                int k = kt * 32 + quad * 8 + jp * 2;
                int v = idx[k];
                int c = v / 9, rem = v - c * 9;
                int i = rem / 3, j2 = rem - i * 3;
                ua = f2bf(x[base + c * (H_IN * W_IN) + i * W_IN + j2]);
            }
            {
                int k = kt * 32 + quad * 8 + jp * 2 + 1;
                int v = idx[k];
                int c = v / 9, rem = v - c * 9;
                int i = rem / 3, j2 = rem - i * 3;
                ub = f2bf(x[base + c * (H_IN * W_IN) + i * W_IN + j2]);
            }
            uu[jp] = (unsigned int)ua | ((unsigned int)ub << 16);
        }
        uint4 pk; pk.x = uu[0]; pk.y = uu[1]; pk.z = uu[2]; pk.w = uu[3];
        *reinterpret_cast<uint4*>(&Bf[(size_t)bid * 2048 + t * 8]) = pk;
    } else {
        const int b = bid - NPACK;
        const int bx = b % 36, by = b / 36;
        const int s0 = bx * 32, o0 = by * 32;
        const int oc = t & 31, sg = t >> 5;
#pragma unroll
        for (int i = 0; i < 4; ++i) {
            int sl = sg * 4 + i;
            tile[sl][oc] = w[(s0 + sl) * OUTC + o0 + oc];
        }
        __syncthreads();
        const int ol = t >> 3, sq = t & 7;
        unsigned int u0 = (unsigned int)f2bf(tile[sq * 4 + 0][ol]) |
                          ((unsigned int)f2bf(tile[sq * 4 + 1][ol]) << 16);
        unsigned int u1 = (unsigned int)f2bf(tile[sq * 4 + 2][ol]) |
                          ((unsigned int)f2bf(tile[sq * 4 + 3][ol]) << 16);
        uint2 pk; pk.x = u0; pk.y = u1;
        const size_t fi =
            (((((size_t)(by >> 1) * KITER + bx) * 4 + ((by * 2 + (ol >> 4)) & 3)) * 64
              + (sq >> 1) * 16 + (ol & 15)) * 8) + (sq & 1) * 4;
        *reinterpret_cast<uint2*>(&wTf[fi]) = pk;
    }
}

// ---------------------------------------------------------------------------
// gemmA: per step per wave: 1 gl_lds16 (B quarter, coalesced), 2 dwordx4
// (A frags), 4 ds_read_b128 (each 16-lane group reads contiguous 256B ->
// conflict-free), 8 MFMA. No gathers, no pack VALU, no koS. LDS 8KB.
// Ledger: top-of-step outstanding = A(kt)[2]; issue [Bgl(kt+1), A(kt+1)x2]
//   -> 5; vmcnt(3) drains A(kt) (MFMA operands); after MFMA vmcnt(2)
//   drains Bgl(kt+1) (Bs[q] complete); barrier -> Bs[q] visible / Bs[p]
//   reads done block-wide. Prologue: [Bgl(0), A(0)x2], vmcnt(2), barrier.
// Cross-wave: Bs[q] writes (gl_lds this step) vs reads (prev step) are
// separated by the prev barrier; reads complete before mid-step lgkm(0).
// ---------------------------------------------------------------------------
__global__ __launch_bounds__(256, 4)
void gemmA_kernel(const unsigned short* __restrict__ wTf,
                  const unsigned short* __restrict__ Bf,
                  float* __restrict__ out) {
    __shared__ __align__(16) unsigned short Bs[2][2048];   // 2 x 4KB frag-order tiles

    const int t    = threadIdx.x;
    const int wave = t >> 6;
    const int lane = t & 63;
    const int quad = lane >> 4;
    const int lo   = lane & 15;

    const int bid = blockIdx.x;
    const int mt  = bid % NMT;
    const int ot  = bid / NMT;                     // ot-siblings 240 apart -> same XCD
    const int oBase = ot * TO;
    const int mBase = mt * TM;

    // A fragment base (R12-verified mapping)
    const int ow64 = ot * 2 + (wave >> 1);
    const int idx0 = (wave * 2) & 3;
    const unsigned short* aP =
        wTf + ((size_t)ow64 * KITER * 4 + idx0) * 512 + (size_t)lane * 8;
    // B tile base for this (mt, wave-quarter)
    const unsigned short* bfP =
        Bf + (size_t)mt * KITER * 2048 + wave * 512 + (size_t)lane * 8;

    unsigned short* ldst0 = &Bs[0][wave * 512];
    unsigned short* ldst1 = &Bs[1][wave * 512];
    const unsigned short* bRd0 = &Bs[0][lane * 8];
    const unsigned short* bRd1 = &Bs[1][lane * 8];

    f32x4 acc[2][4] = {};
    bf16x8 aR[2][2];

    // ---- prologue: Bgl(0)->Bs[0]; A(0)->aR[0]; drain Bgl only ----
    gl_lds16(bfP, ldst0);
    aR[0][0] = *(const bf16x8*)(aP);
    aR[0][1] = *(const bf16x8*)(aP + 512);
    asm volatile("s_waitcnt vmcnt(2)" ::: "memory");   // Bgl(0) done
    __builtin_amdgcn_s_barrier();                      // Bs[0] visible

    // ---- main loop ----
#pragma unroll 2
    for (int kt = 0; kt < KITER; ++kt) {
        const int p = kt & 1, q = p ^ 1;
        const int k1 = (kt + 1 < KITER ? kt + 1 : KITER - 1);

        gl_lds16(bfP + (size_t)k1 * 2048, q ? ldst1 : ldst0);
        aR[q][0] = *(const bf16x8*)(aP + (size_t)(k1 * 4) * 512);
        aR[q][1] = *(const bf16x8*)(aP + (size_t)(k1 * 4 + 1) * 512);

        bf16x8 b[4];
        const unsigned short* br = p ? bRd1 : bRd0;
#pragma unroll
        for (int ns = 0; ns < 4; ++ns)
            b[ns] = *(const bf16x8*)(br + ns * 512);
        asm volatile("s_waitcnt lgkmcnt(0)" ::: "memory");  // b frags in regs
        __builtin_amdgcn_sched_barrier(0);                  // rule #18 fence
        asm volatile("s_waitcnt vmcnt(3)" ::: "memory");    // A(kt) in regs

#pragma unroll
        for (int ms = 0; ms < 2; ++ms)
#pragma unroll
            for (int ns = 0; ns < 4; ++ns)
                acc[ms][ns] = __builtin_amdgcn_mfma_f32_16x16x32_bf16(
                    aR[p][ms], b[ns], acc[ms][ns], 0, 0, 0);

        asm volatile("s_waitcnt vmcnt(2)" ::: "memory");    // Bgl(kt+1) done
        __builtin_amdgcn_s_barrier();
    }

    // Epilogue (R12-verified): D row = o (quad*4+r), col = m (lane&15).
#pragma unroll
    for (int ns = 0; ns < 4; ++ns) {
        const int mh  = mBase + ns * 16 + lo;
        const int xwe = mh & 31;
        const int ryg = mh >> 5;
        const int n = ryg / 30, y = ryg - n * 30;
        if (xwe < OW) {
            const size_t ob = (size_t)n * (OUTC * OUT_SP) + (size_t)y * OW + xwe;
#pragma unroll
            for (int ms = 0; ms < 2; ++ms) {
                const int o0 = oBase + wave * 32 + ms * 16 + quad * 4;
#pragma unroll
                for (int r = 0; r < 4; ++r)
                    out[ob + (size_t)(o0 + r) * OUT_SP] = acc[ms][ns][r];
            }
        }
    }
}

// ===========================================================================
// PATH B (fallback, ws too small): R12 kernels verbatim (measured 104us).
// ===========================================================================
__global__ void prepB_kernel(const int* __restrict__ idx, const float* __restrict__ w,
                             int* __restrict__ koff, unsigned short* __restrict__ wTf) {
    __shared__ float tile[32][33];
    const int bx = blockIdx.x, by = blockIdx.y, t = threadIdx.x;
    if (by == 0) {
        int k = bx * 256 + t;
        if (k < K_SEL) {
            int v = idx[k];
            int c = v / 9, rem = v - c * 9;
            int i = rem / 3, j = rem - i * 3;
            koff[k] = c * (H_IN * W_IN) + i * W_IN + j;
        }
    }
    const int s0 = bx * 32, o0 = by * 32;
    const int oc = t & 31, sg = t >> 5;
#pragma unroll
    for (int i = 0; i < 4; ++i) {
        int sl = sg * 4 + i;
        tile[sl][oc] = w[(s0 + sl) * OUTC + o0 + oc];
    }
    __syncthreads();
    const int ol = t >> 3, sq = t & 7;
    unsigned int u0 = (unsigned int)f2bf(tile[sq * 4 + 0][ol]) |
                      ((unsigned int)f2bf(tile[sq * 4 + 1][ol]) << 16);
    unsigned int u1 = (unsigned int)f2bf(tile[sq * 4 + 2][ol]) |
                      ((unsigned int)f2bf(tile[sq * 4 + 3][ol]) << 16);
    uint2 pk; pk.x = u0; pk.y = u1;
    const size_t fi =
        (((((size_t)(by >> 1) * KITER + bx) * 4 + ((by * 2 + (ol >> 4)) & 3)) * 64
          + (sq >> 1) * 16 + (ol & 15)) * 8) + (sq & 1) * 4;
    *reinterpret_cast<uint2*>(&wTf[fi]) = pk;
}

__global__ __launch_bounds__(256, 4)
void gemmB_kernel(const unsigned short* __restrict__ wTf, const float* __restrict__ x,
                  const int* __restrict__ koff, float* __restrict__ out) {
    __shared__ __align__(16) unsigned short Bs[2][TM * BSTR];
    __shared__ int koS[K_SEL];
    const int t = threadIdx.x, wave = t >> 6, lane = t & 63;
    const int quad = lane >> 4, lo = lane & 15;
    const int bid = blockIdx.x, mt = bid % NMT, ot = bid / NMT;
    const int oBase = ot * TO, mBase = mt * TM;
    for (int i = t; i < K_SEL; i += 256) koS[i] = koff[i];
    const int xw = t & 31, xwc = min(xw, 29);
    int basex[2];
#pragma unroll
    for (int ry = 0; ry < 2; ++ry) {
        int ryg = mt * 2 + ry;
        int n = ryg / 30, y = ryg - n * 30;
        basex[ry] = n * CHW + y * W_IN + xwc;
    }
    const int kq4 = t >> 5, ks = kq4 * 4;
    const int ow64 = ot * 2 + (wave >> 1);
    const int idx0 = (wave * 2) & 3;
    const unsigned short* aP =
        wTf + ((size_t)ow64 * KITER * 4 + idx0) * 512 + (size_t)lane * 8;
    const unsigned short* bB[2] = {
        &Bs[0][lo * BSTR + quad * 8], &Bs[1][lo * BSTR + quad * 8] };
    unsigned short* bW[2] = {
        &Bs[0][xw * BSTR + ks], &Bs[1][xw * BSTR + ks] };
    __syncthreads();
    f32x4 acc[2][4] = {};
    bf16x8 aR[2][2];
    float v[2][2][4];
    {
        int4 k4 = *(const int4*)&koS[ks];
#pragma unroll
        for (int ry = 0; ry < 2; ++ry)
#pragma unroll
            for (int j = 0; j < 4; ++j)
                v[0][ry][j] = x[basex[ry] + ((const int*)&k4)[j]];
    }
    asm volatile("s_waitcnt vmcnt(0)" ::: "memory");
#pragma unroll
    for (int ry = 0; ry < 2; ++ry) {
        unsigned int u0 = (unsigned int)f2bf(v[0][ry][0]) |
                          ((unsigned int)f2bf(v[0][ry][1]) << 16);
        unsigned int u1 = (unsigned int)f2bf(v[0][ry][2]) |
                          ((unsigned int)f2bf(v[0][ry][3]) << 16);
        uint2 pk; pk.x = u0; pk.y = u1;
        *reinterpret_cast<uint2*>(bW[0] + ry * 32 * BSTR) = pk;
    }
#pragma unroll
    for (int ms = 0; ms < 2; ++ms)
        aR[0][ms] = *(const bf16x8*)(aP + (size_t)ms * 512);
    {
        int4 k4 = *(const int4*)&koS[32 + ks];
#pragma unroll
        for (int ry = 0; ry < 2; ++ry)
#pragma unroll
            for (int j = 0; j < 4; ++j)
                v[1][ry][j] = x[basex[ry] + ((const int*)&k4)[j]];
    }
    asm volatile("s_waitcnt lgkmcnt(0)" ::: "memory");
    __builtin_amdgcn_s_barrier();
#pragma unroll 2
    for (int kt = 0; kt < KITER; ++kt) {
        const int p = kt & 1, q = p ^ 1;
        bf16x8 b[4];
#pragma unroll
        for (int ns = 0; ns < 4; ++ns)
            b[ns] = *(const bf16x8*)(bB[p] + ns * 16 * BSTR);
        {
            const int k1 = (kt + 1 < KITER ? kt + 1 : KITER - 1);
#pragma unroll
            for (int ms = 0; ms < 2; ++ms)
                aR[q][ms] = *(const bf16x8*)(aP + (size_t)(k1 * 4 + ms) * 512);
        }
        {
            const int k2 = (kt + 2 < KITER ? kt + 2 : KITER - 1) * 32;
            int4 k4 = *(const int4*)&koS[k2 + ks];
#pragma unroll
            for (int ry = 0; ry < 2; ++ry)
#pragma unroll
                for (int j = 0; j < 4; ++j)
                    v[p][ry][j] = x[basex[ry] + ((const int*)&k4)[j]];
        }
        asm volatile("s_waitcnt vmcnt(10)" ::: "memory");
        asm volatile("s_waitcnt lgkmcnt(0)" ::: "memory");
        __builtin_amdgcn_sched_barrier(0);
#pragma unroll
        for (int ry = 0; ry < 2; ++ry) {
            unsigned int u0 = (unsigned int)f2bf(v[q][ry][0]) |
                              ((unsigned int)f2bf(v[q][ry][1]) << 16);
            unsigned int u1 = (unsigned int)f2bf(v[q][ry][2]) |
                              ((unsigned int)f2bf(v[q][ry][3]) << 16);
            uint2 pk; pk.x = u0; pk.y = u1;
            *reinterpret_cast<uint2*>(bW[q] + ry * 32 * BSTR) = pk;
        }
#pragma unroll
        for (int ms = 0; ms < 2; ++ms)
#pragma unroll
            for (int ns = 0; ns < 4; ++ns)
                acc[ms][ns] = __builtin_amdgcn_mfma_f32_16x16x32_bf16(
                    aR[p][ms], b[ns], acc[ms][ns], 0, 0, 0);
        asm volatile("s_waitcnt lgkmcnt(0)" ::: "memory");
        __builtin_amdgcn_s_barrier();
    }
#pragma unroll
    for (int ns = 0; ns < 4; ++ns) {
        const int mh  = mBase + ns * 16 + lo;
        const int xwe = mh & 31;
        const int ryg = mh >> 5;
        const int n = ryg / 30, y = ryg - n * 30;
        if (xwe < OW) {
            const size_t ob = (size_t)n * (OUTC * OUT_SP) + (size_t)y * OW + xwe;
#pragma unroll
            for (int ms = 0; ms < 2; ++ms) {
                const int o0 = oBase + wave * 32 + ms * 16 + quad * 4;
#pragma unroll
                for (int r = 0; r < 4; ++r)
                    out[ob + (size_t)(o0 + r) * OUT_SP] = acc[ms][ns][r];
            }
        }
    }
}

// ---------------------------------------------------------------------------
extern "C" void kernel_launch(void* const* d_in, const int* in_sizes, int n_in,
                              void* d_out, int out_size, void* d_ws, size_t ws_size,
                              hipStream_t stream) {
    const float* x   = (const float*)d_in[0];
    const float* w   = (const float*)d_in[1];
    const int*   idx = (const int*)d_in[2];
    float*       out = (float*)d_out;
    char* ws = (char*)d_ws;

    if (ws_size >= (size_t)WTF_BYTES + BF_BYTES) {
        // PATH A: ws = wTf 1.18MB | Bf 35.4MB (fragment-packed im2col)
        unsigned short* wTf = (unsigned short*)ws;
        unsigned short* Bf  = (unsigned short*)(ws + WTF_BYTES);
        prepA_kernel<<<dim3(NPACK + NPREPW), dim3(256), 0, stream>>>(
            idx, w, x, wTf, Bf);
        gemmA_kernel<<<dim3(NMT * NOT), dim3(256), 0, stream>>>(wTf, Bf, out);
    } else {
        // PATH B (R12 fallback): ws = koff 4608B | wTf 1.18MB
        int*            koff = (int*)ws;
        unsigned short* wTf  = (unsigned short*)(ws + 4608);
        prepB_kernel<<<dim3(K_SEL / 32, OUTC / 32), dim3(256), 0, stream>>>(
            idx, w, koff, wTf);
        gemmB_kernel<<<dim3(NMT * NOT), dim3(256), 0, stream>>>(wTf, x, koff, out);
    }
}